// Round 7
// baseline (91.615 us; speedup 1.0000x reference)
//
#include <hip/hip_runtime.h>
#include <math.h>

// ============================================================================
// DIAGNOSTIC ROUND: reps=8 amplifies pass1 ref-scan and pass2 slice-min with
// the min carried across reps (result bit-identical; runtime trip count +
// rep-rotated addressing defeat DCE/LICM). Purpose: (a) put our kernels in
// rocprof's top-5 to finally see VALUBusy/LDS-conflict/occupancy; (b) solve
// t1+t2 = (dur - 21.3)/7 to separate compute from graph-node overhead.
// ============================================================================

typedef float v2f __attribute__((ext_vector_type(2)));

#if __has_builtin(__builtin_elementwise_fma)
#define FMA2(a, b, c) __builtin_elementwise_fma((a), (b), (c))
#else
static __device__ __forceinline__ v2f FMA2(v2f a, v2f b, v2f c) {
    v2f r; r.x = fmaf(a.x, b.x, c.x); r.y = fmaf(a.y, b.y, c.y); return r;
}
#endif

#define NBATCH 8
#define PTOT   4096
#define NG     2048              // points per group
#define S      16                // ref slices per problem
#define SLEN   (NG / S)          // 128 refs per slice
#define QPT    8                 // queries per thread (consecutive)
#define NT     256               // threads per block
#define NPROB  32                // 8 batches x 2 groups x 2 directions
#define NBLK1  (NPROB * S)       // 512 blocks, pass 1
#define NPART  (NPROB * S * NG)  // 1M floats (4 MB)

__global__ __launch_bounds__(256) void chamfer_pass1(
    const float* __restrict__ x, const float* __restrict__ y,
    float* __restrict__ pmin, int reps)
{
    __shared__ float  raw[SLEN * 3];     // 1.5 KiB
    __shared__ float4 refX[SLEN / 4];
    __shared__ float4 refY[SLEN / 4];
    __shared__ float4 refZ[SLEN / 4];
    __shared__ float4 refW[SLEN / 4];    // |r|^2

    const int blk   = blockIdx.x;
    const int tid   = threadIdx.x;
    const int slice = blk & (S - 1);
    const int prob  = blk >> 4;
    const int dir   = prob >> 4;
    const int bg    = prob & 15;
    const int b     = bg >> 1;
    const int g     = bg & 1;

    const float* qb = (dir == 0 ? x : y) + (size_t)(b * PTOT + g * NG) * 3;
    const float* rb = (dir == 0 ? y : x) + (size_t)(b * PTOT + g * NG) * 3;

    if (tid < (SLEN * 3) / 4) {
        float4 v = ((const float4*)(rb + slice * SLEN * 3))[tid];
        ((float4*)raw)[tid] = v;
    }

    float4 qv[6];
    {
        const float4* qp = (const float4*)(qb + (size_t)tid * QPT * 3);
        #pragma unroll
        for (int i = 0; i < 6; i++) qv[i] = qp[i];
    }

    __syncthreads();

    if (tid < SLEN / 4) {
        const float* p = raw + tid * 12;
        float x0 = p[0], y0 = p[1],  z0 = p[2];
        float x1 = p[3], y1 = p[4],  z1 = p[5];
        float x2 = p[6], y2 = p[7],  z2 = p[8];
        float x3 = p[9], y3 = p[10], z3 = p[11];
        refX[tid] = make_float4(x0, x1, x2, x3);
        refY[tid] = make_float4(y0, y1, y2, y3);
        refZ[tid] = make_float4(z0, z1, z2, z3);
        refW[tid] = make_float4(fmaf(x0, x0, fmaf(y0, y0, z0 * z0)),
                                fmaf(x1, x1, fmaf(y1, y1, z1 * z1)),
                                fmaf(x2, x2, fmaf(y2, y2, z2 * z2)),
                                fmaf(x3, x3, fmaf(y3, y3, z3 * z3)));
    }

    v2f ax2[QPT], ay2[QPT], az2[QPT];
    float qn[QPT], mn[QPT];
    const float* qf = reinterpret_cast<const float*>(qv);
    #pragma unroll
    for (int k = 0; k < QPT; k++) {
        float qx = qf[k * 3 + 0];
        float qy = qf[k * 3 + 1];
        float qz = qf[k * 3 + 2];
        float ax = -2.0f * qx, ay = -2.0f * qy, az = -2.0f * qz;
        ax2[k] = (v2f){ax, ax};
        ay2[k] = (v2f){ay, ay};
        az2[k] = (v2f){az, az};
        qn[k] = fmaf(qx, qx, fmaf(qy, qy, qz * qz));
        mn[k] = 3.4e38f;
    }

    __syncthreads();

    // reps x identical scan; mn carried -> same result, not elidable
    // (runtime trip count; LDS re-read each rep).
    for (int rep = 0; rep < reps; ++rep) {
        #pragma unroll 2
        for (int n4 = 0; n4 < SLEN / 4; n4++) {
            float4 X = refX[n4], Y = refY[n4], Z = refZ[n4], W = refW[n4];
            v2f X01 = (v2f){X.x, X.y}, X23 = (v2f){X.z, X.w};
            v2f Y01 = (v2f){Y.x, Y.y}, Y23 = (v2f){Y.z, Y.w};
            v2f Z01 = (v2f){Z.x, Z.y}, Z23 = (v2f){Z.z, Z.w};
            v2f W01 = (v2f){W.x, W.y}, W23 = (v2f){W.z, W.w};
            #pragma unroll
            for (int k = 0; k < QPT; k++) {
                v2f t01 = FMA2(X01, ax2[k], W01);
                t01     = FMA2(Y01, ay2[k], t01);
                t01     = FMA2(Z01, az2[k], t01);
                v2f t23 = FMA2(X23, ax2[k], W23);
                t23     = FMA2(Y23, ay2[k], t23);
                t23     = FMA2(Z23, az2[k], t23);
                mn[k] = fminf(fminf(t01.x, t01.y), mn[k]);
                mn[k] = fminf(fminf(t23.x, t23.y), mn[k]);
            }
        }
    }

    float* op = pmin + (size_t)(prob * S + slice) * NG + tid * QPT;
    #pragma unroll
    for (int k = 0; k < QPT; k++)
        op[k] = mn[k] + qn[k];
}

__global__ __launch_bounds__(256) void chamfer_pass2(
    const float* __restrict__ pmin, float* __restrict__ bsum, int reps)
{
    __shared__ float s4[4];
    const int gid  = blockIdx.x * 256 + threadIdx.x;
    const int prob = gid >> 11;
    const int q    = gid & (NG - 1);

    float m0 = 3.4e38f, m1 = 3.4e38f;
    // rep-rotated slice index: same set of addresses each rep (same min),
    // but rep-dependent addressing defeats LICM of the loads.
    for (int rep = 0; rep < reps; ++rep) {
        #pragma unroll
        for (int s = 0; s < S; s += 2) {
            int s0 = (s + rep) & (S - 1);
            int s1 = (s + 1 + rep) & (S - 1);
            m0 = fminf(m0, pmin[(size_t)(prob * S + s0) * NG + q]);
            m1 = fminf(m1, pmin[(size_t)(prob * S + s1) * NG + q]);
        }
    }
    float m = fminf(m0, m1);

    float d = sqrtf(fmaxf(m, 0.0f));

    for (int off = 32; off > 0; off >>= 1)
        d += __shfl_down(d, off, 64);
    if ((threadIdx.x & 63) == 0) s4[threadIdx.x >> 6] = d;
    __syncthreads();
    if (threadIdx.x == 0)
        bsum[blockIdx.x] = (s4[0] + s4[1]) + (s4[2] + s4[3]);
}

__global__ __launch_bounds__(256) void chamfer_pass3(
    const float* __restrict__ bsum, float* __restrict__ out)
{
    __shared__ float s4[4];
    const int tid = threadIdx.x;
    float v = bsum[tid];
    for (int off = 32; off > 0; off >>= 1)
        v += __shfl_down(v, off, 64);
    if ((tid & 63) == 0) s4[tid >> 6] = v;
    __syncthreads();
    if (tid == 0)
        out[0] = ((s4[0] + s4[1]) + (s4[2] + s4[3])) * (1.0f / 16384.0f);
}

extern "C" void kernel_launch(void* const* d_in, const int* in_sizes, int n_in,
                              void* d_out, int out_size, void* d_ws, size_t ws_size,
                              hipStream_t stream) {
    const float* x = (const float*)d_in[0];
    const float* y = (const float*)d_in[1];
    float* out  = (float*)d_out;
    float* pmin = (float*)d_ws;                 // 1M floats (4 MB)
    float* bsum = pmin + NPART;                 // 256 floats

    const int reps = 8;   // DIAGNOSTIC amplification
    chamfer_pass1<<<NBLK1, NT, 0, stream>>>(x, y, pmin, reps);
    chamfer_pass2<<<256, NT, 0, stream>>>(pmin, bsum, reps);
    chamfer_pass3<<<1, NT, 0, stream>>>(bsum, out);
}

// Round 8
// 24.462 us; speedup vs baseline: 3.7452x; 3.7452x over previous
//
#include <hip/hip_runtime.h>
#include <math.h>

typedef float v2f __attribute__((ext_vector_type(2)));

// Real packed fp32 ops (VOP3P, gfx90a+/gfx950). NOTE: no v_pk_min_f32 exists;
// min stays scalar v_min3_f32 on the two result halves.
static __device__ __forceinline__ v2f pkfma(v2f a, v2f b, v2f c) {
    v2f d;
    asm("v_pk_fma_f32 %0, %1, %2, %3" : "=v"(d) : "v"(a), "v"(b), "v"(c));
    return d;
}
static __device__ __forceinline__ v2f pkmul(v2f a, v2f b) {
    v2f d;
    asm("v_pk_mul_f32 %0, %1, %2" : "=v"(d) : "v"(a), "v"(b));
    return d;
}

#define NBATCH 8
#define PTOT   4096
#define NG     2048              // points per group
#define S      32                // ref slices per problem
#define SLEN   (NG / S)          // 64 refs per slice
#define QPT    8                 // queries per thread (consecutive)
#define NT     256               // threads per block
#define NPROB  32                // 8 batches x 2 groups x 2 directions
#define NBLK1  (NPROB * S)       // 1024 blocks -> 4 blocks/CU -> 4 waves/SIMD
#define NPART  (NPROB * S * NG)  // 2M floats (8 MB)

// Pass 1: one block = (problem, slice of 64 refs). Refs staged to LDS as
// SoA-of-float4 X/Y/Z only (|r|^2 recomputed per iter per wave, shared by 8
// queries) -> 3 broadcast ds_read_b128 per 4 refs. Inner loop is guaranteed
// packed: per 4 refs x query = 6 v_pk_fma_f32 + 2 v_min3_f32 = 2.0 instr/pair.
__global__ __launch_bounds__(256, 4) void chamfer_pass1(
    const float* __restrict__ x, const float* __restrict__ y,
    float* __restrict__ pmin)
{
    __shared__ float  raw[SLEN * 3];     // 768 B
    __shared__ float4 refX[SLEN / 4];    // 16 x 16B
    __shared__ float4 refY[SLEN / 4];
    __shared__ float4 refZ[SLEN / 4];

    const int blk   = blockIdx.x;
    const int tid   = threadIdx.x;
    const int slice = blk & (S - 1);
    const int prob  = blk >> 5;              // 0..31
    const int dir   = prob >> 4;             // 0: x->y, 1: y->x
    const int bg    = prob & 15;
    const int b     = bg >> 1;               // batch
    const int g     = bg & 1;                // group

    const float* qb = (dir == 0 ? x : y) + (size_t)(b * PTOT + g * NG) * 3;
    const float* rb = (dir == 0 ? y : x) + (size_t)(b * PTOT + g * NG) * 3;

    // Stage 64 refs: 192 floats = 48 float4 (768B slice stride -> 16B aligned).
    if (tid < 48) {
        float4 v = ((const float4*)(rb + slice * SLEN * 3))[tid];
        ((float4*)raw)[tid] = v;
    }

    // Query loads hoisted above the barrier (8 q x 3 = 24 floats = 6 float4).
    float4 qv[6];
    {
        const float4* qp = (const float4*)(qb + (size_t)tid * QPT * 3);
        #pragma unroll
        for (int i = 0; i < 6; i++) qv[i] = qp[i];
    }

    __syncthreads();

    // Transpose to SoA-of-float4 (16 threads, one 4-ref group each).
    if (tid < SLEN / 4) {
        const float* p = raw + tid * 12;
        refX[tid] = make_float4(p[0], p[3], p[6], p[9]);
        refY[tid] = make_float4(p[1], p[4], p[7], p[10]);
        refZ[tid] = make_float4(p[2], p[5], p[8], p[11]);
    }

    // Packed coefficients (duplicated halves), 48 VGPR.
    v2f ax2[QPT], ay2[QPT], az2[QPT];
    float qn[QPT], mn[QPT];
    const float* qf = reinterpret_cast<const float*>(qv);
    #pragma unroll
    for (int k = 0; k < QPT; k++) {
        float qx = qf[k * 3 + 0];
        float qy = qf[k * 3 + 1];
        float qz = qf[k * 3 + 2];
        float ax = -2.0f * qx, ay = -2.0f * qy, az = -2.0f * qz;
        ax2[k] = (v2f){ax, ax};
        ay2[k] = (v2f){ay, ay};
        az2[k] = (v2f){az, az};
        qn[k] = fmaf(qx, qx, fmaf(qy, qy, qz * qz));
        mn[k] = 3.4e38f;
    }

    __syncthreads();

    // 16 iters; per iter: 3 broadcast ds_read_b128 + 6 pk-ops (W) +
    // 8 q x (6 pk_fma + 2 min3) = 70 VALU instr.
    #pragma unroll 2
    for (int n4 = 0; n4 < SLEN / 4; n4++) {
        float4 X = refX[n4], Y = refY[n4], Z = refZ[n4];
        v2f X01 = (v2f){X.x, X.y}, X23 = (v2f){X.z, X.w};
        v2f Y01 = (v2f){Y.x, Y.y}, Y23 = (v2f){Y.z, Y.w};
        v2f Z01 = (v2f){Z.x, Z.y}, Z23 = (v2f){Z.z, Z.w};
        v2f W01 = pkmul(X01, X01);
        W01 = pkfma(Y01, Y01, W01);
        W01 = pkfma(Z01, Z01, W01);
        v2f W23 = pkmul(X23, X23);
        W23 = pkfma(Y23, Y23, W23);
        W23 = pkfma(Z23, Z23, W23);
        #pragma unroll
        for (int k = 0; k < QPT; k++) {
            v2f t01 = pkfma(X01, ax2[k], W01);
            t01     = pkfma(Y01, ay2[k], t01);
            t01     = pkfma(Z01, az2[k], t01);
            v2f t23 = pkfma(X23, ax2[k], W23);
            t23     = pkfma(Y23, ay2[k], t23);
            t23     = pkfma(Z23, az2[k], t23);
            mn[k] = fminf(fminf(t01.x, t01.y), mn[k]);   // v_min3_f32
            mn[k] = fminf(fminf(t23.x, t23.y), mn[k]);   // v_min3_f32
        }
    }

    // 8 contiguous floats per thread -> 2x global_store_dwordx4.
    float* op = pmin + (size_t)(prob * S + slice) * NG + tid * QPT;
    #pragma unroll
    for (int i = 0; i < 2; i++)
        ((float4*)op)[i] = make_float4(mn[4*i+0] + qn[4*i+0],
                                       mn[4*i+1] + qn[4*i+1],
                                       mn[4*i+2] + qn[4*i+2],
                                       mn[4*i+3] + qn[4*i+3]);
}

// Pass 2: per (problem, query) min over the 32 slices, sqrt, block-sum.
__global__ __launch_bounds__(256) void chamfer_pass2(
    const float* __restrict__ pmin, float* __restrict__ bsum)
{
    __shared__ float s4[4];
    const int gid  = blockIdx.x * 256 + threadIdx.x;   // 0..65535
    const int prob = gid >> 11;                        // /2048
    const int q    = gid & (NG - 1);

    float m0 = 3.4e38f, m1 = 3.4e38f;
    #pragma unroll
    for (int s = 0; s < S; s += 4) {
        float l0 = pmin[(size_t)(prob * S + s + 0) * NG + q];
        float l1 = pmin[(size_t)(prob * S + s + 1) * NG + q];
        float l2 = pmin[(size_t)(prob * S + s + 2) * NG + q];
        float l3 = pmin[(size_t)(prob * S + s + 3) * NG + q];
        m0 = fminf(fminf(l0, l1), m0);   // v_min3_f32
        m1 = fminf(fminf(l2, l3), m1);   // v_min3_f32
    }
    float m = fminf(m0, m1);

    float d = sqrtf(fmaxf(m, 0.0f));   // guard cancellation

    for (int off = 32; off > 0; off >>= 1)
        d += __shfl_down(d, off, 64);
    if ((threadIdx.x & 63) == 0) s4[threadIdx.x >> 6] = d;
    __syncthreads();
    if (threadIdx.x == 0)
        bsum[blockIdx.x] = (s4[0] + s4[1]) + (s4[2] + s4[3]);
}

// Pass 3: deterministic reduction of the 256 block sums.
__global__ __launch_bounds__(256) void chamfer_pass3(
    const float* __restrict__ bsum, float* __restrict__ out)
{
    __shared__ float s4[4];
    const int tid = threadIdx.x;
    float v = bsum[tid];
    for (int off = 32; off > 0; off >>= 1)
        v += __shfl_down(v, off, 64);
    if ((tid & 63) == 0) s4[tid >> 6] = v;
    __syncthreads();
    if (tid == 0)
        out[0] = ((s4[0] + s4[1]) + (s4[2] + s4[3])) * (1.0f / 16384.0f);
}

extern "C" void kernel_launch(void* const* d_in, const int* in_sizes, int n_in,
                              void* d_out, int out_size, void* d_ws, size_t ws_size,
                              hipStream_t stream) {
    const float* x = (const float*)d_in[0];
    const float* y = (const float*)d_in[1];
    float* out  = (float*)d_out;
    float* pmin = (float*)d_ws;                 // 2M floats (8 MB)
    float* bsum = pmin + NPART;                 // 256 floats

    chamfer_pass1<<<NBLK1, NT, 0, stream>>>(x, y, pmin);
    chamfer_pass2<<<256, NT, 0, stream>>>(pmin, bsum);
    chamfer_pass3<<<1, NT, 0, stream>>>(bsum, out);
}

// Round 9
// 22.107 us; speedup vs baseline: 4.1442x; 1.1065x over previous
//
#include <hip/hip_runtime.h>
#include <math.h>

typedef float v2f __attribute__((ext_vector_type(2)));

// Packed d^2 accumulate for a QUERY PAIR against one ref point.
// Ref arrives as its natural float4 subreg pairs xy=(x,y), zw=(z,w=|r|^2);
// op_sel/op_sel_hi broadcast the needed scalar half to both lanes, so no
// duplicated-coefficient registers are needed anywhere.
//   t = x*axp + w ; t = y*ayp + t ; t = z*azp + t     (per-lane fp32 FMA)
static __device__ __forceinline__ v2f pk3(v2f xy, v2f zw, v2f axp, v2f ayp, v2f azp) {
    v2f t;
    asm("v_pk_fma_f32 %0, %1, %2, %3 op_sel:[0,0,1] op_sel_hi:[0,1,1]"  // x*axp + w
        : "=v"(t) : "v"(xy), "v"(axp), "v"(zw));
    asm("v_pk_fma_f32 %0, %1, %2, %0 op_sel:[1,0,0] op_sel_hi:[1,1,1]"  // y*ayp + t
        : "+v"(t) : "v"(xy), "v"(ayp));
    asm("v_pk_fma_f32 %0, %1, %2, %0 op_sel:[0,0,0] op_sel_hi:[0,1,1]"  // z*azp + t
        : "+v"(t) : "v"(zw), "v"(azp));
    return t;
}

#define NBATCH 8
#define PTOT   4096
#define NG     2048              // points per group
#define S      16                // ref slices per problem
#define SLEN   (NG / S)          // 128 refs per slice
#define QPT    8                 // queries per thread (4 packed pairs)
#define NT     256               // threads per block
#define NPROB  32                // 8 batches x 2 groups x 2 directions
#define NBLK1  (NPROB * S)       // 512 blocks, pass 1
#define NPART  (NPROB * S * NG)  // 1M floats (4 MB)

// Pass 1: identical skeleton to the 21.3us R3 kernel (S=16, QPT=8, AoS float4
// LDS refs, hoisted query loads). Only the inner loop changes: true packed
// VOP3P math at 2.0 instr/pair with no extra register pressure.
__global__ __launch_bounds__(256) void chamfer_pass1(
    const float* __restrict__ x, const float* __restrict__ y,
    float* __restrict__ pmin)
{
    __shared__ float  raw[SLEN * 3];   // 1.5 KiB
    __shared__ float4 ref[SLEN];       // 2 KiB (x,y,z,|r|^2)

    const int blk   = blockIdx.x;
    const int tid   = threadIdx.x;
    const int slice = blk & (S - 1);
    const int prob  = blk >> 4;              // 0..31
    const int dir   = prob >> 4;             // 0: x->y, 1: y->x
    const int bg    = prob & 15;
    const int b     = bg >> 1;               // batch
    const int g     = bg & 1;                // group

    const float* qb = (dir == 0 ? x : y) + (size_t)(b * PTOT + g * NG) * 3;
    const float* rb = (dir == 0 ? y : x) + (size_t)(b * PTOT + g * NG) * 3;

    // Stage ref slice: 384 floats = 96 float4 (16B-aligned).
    if (tid < (SLEN * 3) / 4) {
        float4 v = ((const float4*)(rb + slice * SLEN * 3))[tid];
        ((float4*)raw)[tid] = v;
    }

    // Query loads hoisted above the barrier (8 q x 3 = 6 float4).
    float4 qv[6];
    {
        const float4* qp = (const float4*)(qb + (size_t)tid * QPT * 3);
        #pragma unroll
        for (int i = 0; i < 6; i++) qv[i] = qp[i];
    }

    __syncthreads();

    // Build AoS ref (x,y,z,|r|^2).
    if (tid < SLEN) {
        float rx = raw[tid * 3 + 0];
        float ry = raw[tid * 3 + 1];
        float rz = raw[tid * 3 + 2];
        ref[tid] = make_float4(rx, ry, rz, fmaf(rx, rx, fmaf(ry, ry, rz * rz)));
    }

    // Query-PAIR packed coefficients: axp[p] = {-2x_{2p}, -2x_{2p+1}} etc.
    // 4 pairs x 3 = 24 VGPR — same footprint as the scalar version.
    v2f axp[4], ayp[4], azp[4], qnp[4], mnp[4];
    const float* qf = reinterpret_cast<const float*>(qv);
    #pragma unroll
    for (int p = 0; p < 4; p++) {
        float qx0 = qf[(2*p) * 3 + 0], qx1 = qf[(2*p+1) * 3 + 0];
        float qy0 = qf[(2*p) * 3 + 1], qy1 = qf[(2*p+1) * 3 + 1];
        float qz0 = qf[(2*p) * 3 + 2], qz1 = qf[(2*p+1) * 3 + 2];
        axp[p] = (v2f){-2.0f * qx0, -2.0f * qx1};
        ayp[p] = (v2f){-2.0f * qy0, -2.0f * qy1};
        azp[p] = (v2f){-2.0f * qz0, -2.0f * qz1};
        qnp[p] = (v2f){fmaf(qx0, qx0, fmaf(qy0, qy0, qz0 * qz0)),
                       fmaf(qx1, qx1, fmaf(qy1, qy1, qz1 * qz1))};
        mnp[p] = (v2f){3.4e38f, 3.4e38f};
    }

    __syncthreads();

    // Per 2 refs: 2 broadcast ds_read_b128 + 4 qpairs x (6 pk_fma + 2 min3)
    // = 32 VALU instr for 16 (q,r) pairs = 2.0 instr/pair.
    #pragma unroll 4
    for (int n = 0; n < SLEN; n += 2) {
        float4 r0 = ref[n + 0];
        float4 r1 = ref[n + 1];
        union { float4 f4; v2f h[2]; } u0, u1;
        u0.f4 = r0; u1.f4 = r1;
        v2f r0xy = u0.h[0], r0zw = u0.h[1];
        v2f r1xy = u1.h[0], r1zw = u1.h[1];
        #pragma unroll
        for (int p = 0; p < 4; p++) {
            v2f t0 = pk3(r0xy, r0zw, axp[p], ayp[p], azp[p]);
            v2f t1 = pk3(r1xy, r1zw, axp[p], ayp[p], azp[p]);
            mnp[p].x = fminf(fminf(t0.x, t1.x), mnp[p].x);   // v_min3_f32
            mnp[p].y = fminf(fminf(t0.y, t1.y), mnp[p].y);   // v_min3_f32
        }
    }

    // 8 contiguous floats -> 2x global_store_dwordx4.
    float res[QPT];
    #pragma unroll
    for (int p = 0; p < 4; p++) {
        res[2*p + 0] = mnp[p].x + qnp[p].x;
        res[2*p + 1] = mnp[p].y + qnp[p].y;
    }
    float* op = pmin + (size_t)(prob * S + slice) * NG + tid * QPT;
    #pragma unroll
    for (int i = 0; i < 2; i++)
        ((float4*)op)[i] = make_float4(res[4*i+0], res[4*i+1], res[4*i+2], res[4*i+3]);
}

// Pass 2: per (problem, query) min over the 16 slices, sqrt, block-sum.
__global__ __launch_bounds__(256) void chamfer_pass2(
    const float* __restrict__ pmin, float* __restrict__ bsum)
{
    __shared__ float s4[4];
    const int gid  = blockIdx.x * 256 + threadIdx.x;   // 0..65535
    const int prob = gid >> 11;                        // /2048
    const int q    = gid & (NG - 1);

    float m0 = 3.4e38f, m1 = 3.4e38f;
    #pragma unroll
    for (int s = 0; s < S; s += 2) {
        m0 = fminf(m0, pmin[(size_t)(prob * S + s) * NG + q]);
        m1 = fminf(m1, pmin[(size_t)(prob * S + s + 1) * NG + q]);
    }
    float m = fminf(m0, m1);

    float d = sqrtf(fmaxf(m, 0.0f));   // guard cancellation

    for (int off = 32; off > 0; off >>= 1)
        d += __shfl_down(d, off, 64);
    if ((threadIdx.x & 63) == 0) s4[threadIdx.x >> 6] = d;
    __syncthreads();
    if (threadIdx.x == 0)
        bsum[blockIdx.x] = (s4[0] + s4[1]) + (s4[2] + s4[3]);
}

// Pass 3: deterministic reduction of the 256 block sums.
__global__ __launch_bounds__(256) void chamfer_pass3(
    const float* __restrict__ bsum, float* __restrict__ out)
{
    __shared__ float s4[4];
    const int tid = threadIdx.x;
    float v = bsum[tid];
    for (int off = 32; off > 0; off >>= 1)
        v += __shfl_down(v, off, 64);
    if ((tid & 63) == 0) s4[tid >> 6] = v;
    __syncthreads();
    if (tid == 0)
        out[0] = ((s4[0] + s4[1]) + (s4[2] + s4[3])) * (1.0f / 16384.0f);
}

extern "C" void kernel_launch(void* const* d_in, const int* in_sizes, int n_in,
                              void* d_out, int out_size, void* d_ws, size_t ws_size,
                              hipStream_t stream) {
    const float* x = (const float*)d_in[0];
    const float* y = (const float*)d_in[1];
    float* out  = (float*)d_out;
    float* pmin = (float*)d_ws;                 // 1M floats (4 MB)
    float* bsum = pmin + NPART;                 // 256 floats

    chamfer_pass1<<<NBLK1, NT, 0, stream>>>(x, y, pmin);
    chamfer_pass2<<<256, NT, 0, stream>>>(pmin, bsum);
    chamfer_pass3<<<1, NT, 0, stream>>>(bsum, out);
}